// Round 6
// baseline (270.044 us; speedup 1.0000x reference)
//
#include <hip/hip_runtime.h>
#include <hip/hip_bf16.h>
#include <math.h>

// GAT layer: B=8, C_in=32, N=2048, L=12, F=32
// out[b,f,w,l] = elu( sum_v Wh[b,l,v,f] * attn[b,v,w] ),
// attn = softmax_v( mask(adj, lrelu(s1[v]+s2[w])) )
//
// Softmax shift = per-batch global max Mb (valid; exp args <= 0).
// Factorized: t = pos ? E1[v]*F1[w] : E2[v]*F2[w];
//   E1=exp(s1), E2=exp(0.2 s1), F1=exp(s2-m), F2=exp(0.2 s2-m), m=lrelu(Mb+s2)
//   pos: s1+s2>0  <=>  E1[v] > exp(-s2[w]).
// Denominator accumulated inside the GEMM; normalized in epilogue.

constexpr int Nn  = 2048;
constexpr int Ln  = 12;
constexpr int Fn  = 32;
constexpr int LF  = Ln * Fn;    // 384
constexpr int NW  = Nn / 32;    // 64 bit-words per column
constexpr int CH  = 128;        // K-chunk (v per LDS stage)
constexpr int NCH = Nn / CH;    // 16
constexpr int WT  = 32;         // w columns per block

typedef short short8 __attribute__((ext_vector_type(8)));   // 8 x bf16 bits
typedef float f32x4  __attribute__((ext_vector_type(4)));

// float -> bf16 bits, round-to-nearest-even (finite inputs only)
static __device__ __forceinline__ unsigned short f2bf(float x) {
    unsigned u = __builtin_bit_cast(unsigned, x);
    u += 0x7FFFu + ((u >> 16) & 1u);
    return (unsigned short)(u >> 16);
}

// ---------------------------------------------------------------------------
// 1. Pack transposed adjacency bitmask: bits[w][vw] bit k = adj[vw*32+k][w] > 0
// ---------------------------------------------------------------------------
__global__ __launch_bounds__(256) void k_adjbits(const int* __restrict__ adj,
                                                 unsigned* __restrict__ bits) {
    int id = blockIdx.x * 256 + threadIdx.x;    // 131072
    int w  = id & (Nn - 1);
    int vw = id >> 11;                          // 0..63
    unsigned m = 0u;
    int base = vw * 32 * Nn + w;
    #pragma unroll
    for (int k = 0; k < 32; ++k)
        m |= (adj[base + k * Nn] > 0 ? 1u : 0u) << k;
    bits[w * NW + vw] = m;
}

// ---------------------------------------------------------------------------
// 2. Wh projection. Block = (8 n) x (12 l) x (32 f) for one b.
//    h staged [row=(n*12+l)][c] (c-contiguous, padded) -> b128 broadcast reads.
//    W column register-resident. WhT staged in LDS, stored as 16B rows.
// ---------------------------------------------------------------------------
__global__ __launch_bounds__(256) void k_wh(const float* __restrict__ h,
                                            const float* __restrict__ W,
                                            const float* __restrict__ a,
                                            unsigned short* __restrict__ WhT,
                                            float* __restrict__ s1,
                                            float* __restrict__ s2,
                                            float* __restrict__ E1,
                                            float* __restrict__ E2) {
    __shared__ float hs[96][33];                 // 12.7 KB, padded
    __shared__ unsigned short T2[8][392];        // 6.3 KB, [n_local][row] padded
    int b  = blockIdx.y;
    int n0 = blockIdx.x * 8;
    int tid = threadIdx.x;

    for (int i = tid; i < 32 * 96; i += 256) {
        int c = i / 96, r = i % 96;              // r = n_local*12 + l
        hs[r][c] = h[(size_t)(b * 32 + c) * (Nn * Ln) + n0 * Ln + r];
    }
    int f  = tid & 31;
    int nl = tid >> 5;
    float Wc[32];
    #pragma unroll
    for (int c = 0; c < 32; ++c) Wc[c] = W[c * 32 + f];
    __syncthreads();

    float last = 0.f;
    #pragma unroll
    for (int l = 0; l < Ln; ++l) {
        const float* hr = &hs[nl * Ln + l][0];
        float acc = 0.f;
        #pragma unroll
        for (int cq = 0; cq < 8; ++cq) {
            f32x4 hv = *(const f32x4*)(hr + cq * 4);
            acc = fmaf(hv[0], Wc[cq * 4 + 0], acc);
            acc = fmaf(hv[1], Wc[cq * 4 + 1], acc);
            acc = fmaf(hv[2], Wc[cq * 4 + 2], acc);
            acc = fmaf(hv[3], Wc[cq * 4 + 3], acc);
        }
        T2[nl][l * 32 + f] = f2bf(acc);
        if (l == Ln - 1) last = acc;
    }
    float r1 = last * a[f];
    float r2 = last * a[Fn + f];
    #pragma unroll
    for (int off = 16; off >= 1; off >>= 1) {
        r1 += __shfl_xor(r1, off);
        r2 += __shfl_xor(r2, off);
    }
    if (f == 0) {
        int n = n0 + nl;
        s1[b * Nn + n] = r1;
        s2[b * Nn + n] = r2;
        E1[b * Nn + n] = __expf(r1);
        E2[b * Nn + n] = __expf(0.2f * r1);
    }
    __syncthreads();
    // store WhT rows: 384 rows x 8 n (16 B contiguous each)
    for (int r = tid; r < LF; r += 256) {
        unsigned d0 = (unsigned)T2[0][r] | ((unsigned)T2[1][r] << 16);
        unsigned d1 = (unsigned)T2[2][r] | ((unsigned)T2[3][r] << 16);
        unsigned d2 = (unsigned)T2[4][r] | ((unsigned)T2[5][r] << 16);
        unsigned d3 = (unsigned)T2[6][r] | ((unsigned)T2[7][r] << 16);
        uint4 val = {d0, d1, d2, d3};
        *(uint4*)&WhT[((size_t)b * LF + r) * Nn + n0] = val;
    }
}

// ---------------------------------------------------------------------------
// 3. Aux: blocks 0-7 = per-batch max of s1; blocks 8-15 = per-column empty flag
// ---------------------------------------------------------------------------
__global__ __launch_bounds__(256) void k_aux(const float* __restrict__ s1,
                                             const unsigned* __restrict__ bits,
                                             float* __restrict__ Mb,
                                             int* __restrict__ empty) {
    if (blockIdx.x < 8) {
        int b = blockIdx.x;
        float m = -1e30f;
        for (int i = threadIdx.x; i < Nn; i += 256) m = fmaxf(m, s1[b * Nn + i]);
        #pragma unroll
        for (int off = 32; off >= 1; off >>= 1) m = fmaxf(m, __shfl_xor(m, off));
        __shared__ float wr[4];
        if ((threadIdx.x & 63) == 0) wr[threadIdx.x >> 6] = m;
        __syncthreads();
        if (threadIdx.x == 0)
            Mb[b] = fmaxf(fmaxf(wr[0], wr[1]), fmaxf(wr[2], wr[3]));
    } else {
        int w = (blockIdx.x - 8) * 256 + threadIdx.x;
        const uint4* p = (const uint4*)(bits + (size_t)w * NW);
        unsigned acc = 0;
        #pragma unroll
        for (int i = 0; i < 16; ++i) { uint4 v = p[i]; acc |= v.x | v.y | v.z | v.w; }
        empty[w] = (acc == 0u) ? 1 : 0;
    }
}

// ---------------------------------------------------------------------------
// 4. Fused aggregation GEMM. Block = 512 thr (8 waves), full M=384 x WT=32 w,
//    one batch (id&7 -> XCD). Software-pipelined: A-fragments for chunk c+1
//    prefetched into registers DURING chunk c's MFMA phase (the vmcnt(0)
//    drain at the per-chunk barrier guarantees they land before use), so the
//    MFMA phase never waits on VMEM. P generated cooperatively into swizzled
//    double-buffered LDS. Denominator in-register; coalesced epilogue via LDS.
// ---------------------------------------------------------------------------
__global__ __launch_bounds__(512, 4) void k_gemm(const unsigned short* __restrict__ WhT,
                                                 const float* __restrict__ s2,
                                                 const float* __restrict__ Mb,
                                                 const float* __restrict__ E1,
                                                 const float* __restrict__ E2,
                                                 const unsigned* __restrict__ bits,
                                                 const int* __restrict__ empty,
                                                 float* __restrict__ out) {
    int id = blockIdx.x;            // 512 = 64 wt * 8 b; id&7==b -> one batch/XCD
    int b_ = id & 7;
    int wt = id >> 3;               // 0..63
    int w0 = wt * WT;
    int tid  = threadIdx.x;
    int lane = tid & 63;
    int wv   = tid >> 6;            // wave 0..7
    int lr   = lane & 15;
    int lg   = lane >> 4;
    int rbase = wv * 48;

    __shared__ unsigned short P[2][WT * CH];   // 2 x 8 KB, XOR-swizzled
    __shared__ float T[LF][17];                // 26.1 KB epilogue transpose
    __shared__ float denom[WT];

    // P-gen mapping: thread = (wl 0..31, vgrp 0..15) -> 8 v
    int vgrp = tid & 15;
    int wl   = tid >> 4;
    int vs   = vgrp * 8;
    int w    = w0 + wl;

    const float* E1b = E1 + (size_t)b_ * Nn;
    const float* E2b = E2 + (size_t)b_ * Nn;
    const unsigned* bw = bits + (size_t)w * NW;

    float s2w = s2[(size_t)b_ * Nn + w];
    float mz  = Mb[b_] + s2w;
    float mw  = fmaxf(mz, 0.2f * mz);          // lrelu
    float F1  = __expf(s2w - mw);
    float F2  = __expf(0.2f * s2w - mw);
    float G   = __expf(-s2w);
    float Uv  = empty[w] ? 1.0f : 0.0f;
    float dsum = 0.f;

    auto gen = [&](int c, int buf) {
        int v0 = c * CH + vs;
        f32x4 e1a = *(const f32x4*)(E1b + v0);
        f32x4 e1c = *(const f32x4*)(E1b + v0 + 4);
        f32x4 e2a = *(const f32x4*)(E2b + v0);
        f32x4 e2c = *(const f32x4*)(E2b + v0 + 4);
        unsigned bm = (bw[v0 >> 5] >> (v0 & 31)) & 0xffu;
        short8 sv;
        #pragma unroll
        for (int j = 0; j < 8; ++j) {
            float e1 = (j < 4) ? e1a[j] : e1c[j - 4];
            float e2 = (j < 4) ? e2a[j] : e2c[j - 4];
            bool pos = e1 > G;
            float t = (pos ? e1 : e2) * (pos ? F1 : F2);
            float p = ((bm >> j) & 1u) ? t : Uv;
            dsum += p;
            sv[j] = (short)f2bf(p);
        }
        int idx = (wl * CH + vs) ^ ((wl & 7) << 3);
        *(short8*)&P[buf][idx] = sv;
    };

    f32x4 acc[3][2];
    #pragma unroll
    for (int r = 0; r < 3; ++r)
        #pragma unroll
        for (int nf = 0; nf < 2; ++nf) acc[r][nf] = (f32x4){0.f, 0.f, 0.f, 0.f};

    const unsigned short* Ab = WhT + (size_t)b_ * LF * Nn;
    const unsigned short* Arow[3];
    #pragma unroll
    for (int r = 0; r < 3; ++r)
        Arow[r] = Ab + (size_t)(rbase + r * 16 + lr) * Nn;

    // rolling A-fragment registers: af[ks][r] holds current chunk's fragments
    short8 af[4][3];
    #pragma unroll
    for (int ks = 0; ks < 4; ++ks)
        #pragma unroll
        for (int r = 0; r < 3; ++r)
            af[ks][r] = *(const short8*)(Arow[r] + ks * 32 + lg * 8);

    gen(0, 0);
    __syncthreads();      // drains af prologue loads + P[0] writes visible

    for (int c = 0; c < NCH; ++c) {
        int nxt = c + 1;
        if (nxt < NCH) gen(nxt, nxt & 1);          // VALU + ds_write (other buf)
        const unsigned short* Pc = &P[c & 1][0];
        #pragma unroll
        for (int ks = 0; ks < 4; ++ks) {
            #pragma unroll
            for (int nf = 0; nf < 2; ++nf) {
                int row = nf * 16 + lr;
                int idx = (row * CH + ks * 32 + lg * 8) ^ ((row & 7) << 3);
                short8 bf = *(const short8*)&Pc[idx];
                #pragma unroll
                for (int r = 0; r < 3; ++r)
                    acc[r][nf] = __builtin_amdgcn_mfma_f32_16x16x32_bf16(af[ks][r], bf, acc[r][nf], 0, 0, 0);
            }
            if (nxt < NCH) {
                // prefetch next chunk's fragments into the slot just consumed;
                // they complete at the barrier's vmcnt drain -> MFMA never waits
                #pragma unroll
                for (int r = 0; r < 3; ++r)
                    af[ks][r] = *(const short8*)(Arow[r] + nxt * CH + ks * 32 + lg * 8);
            }
        }
        __syncthreads();
    }

    // one-time denominator reduction over the 16 v-lanes of each w-group
    #pragma unroll
    for (int off = 1; off < 16; off <<= 1) dsum += __shfl_xor(dsum, off);
    if (vgrp == 0) denom[wl] = dsum;
    __syncthreads();

    // epilogue: per 16-w half, transpose via LDS then 48B-contiguous stores
    int fE  = tid >> 4;             // 0..31
    int wlE = tid & 15;             // 0..15
    #pragma unroll
    for (int nf = 0; nf < 2; ++nf) {
        #pragma unroll
        for (int r = 0; r < 3; ++r)
            #pragma unroll
            for (int q = 0; q < 4; ++q)
                T[rbase + r * 16 + lg * 4 + q][lr] = acc[r][nf][q];
        __syncthreads();
        {
            float rdv = 1.0f / denom[nf * 16 + wlE];
            float vals[12];
            #pragma unroll
            for (int l = 0; l < Ln; ++l) {
                float v = T[l * 32 + fE][wlE] * rdv;
                vals[l] = (v > 0.f) ? v : expm1f(v);
            }
            float* ob = out + ((size_t)(b_ * Fn + fE) * Nn + w0 + nf * 16 + wlE) * Ln;
            *(f32x4*)(ob + 0) = (f32x4){vals[0], vals[1], vals[2], vals[3]};
            *(f32x4*)(ob + 4) = (f32x4){vals[4], vals[5], vals[6], vals[7]};
            *(f32x4*)(ob + 8) = (f32x4){vals[8], vals[9], vals[10], vals[11]};
        }
        __syncthreads();
    }
}

// ---------------------------------------------------------------------------
extern "C" void kernel_launch(void* const* d_in, const int* in_sizes, int n_in,
                              void* d_out, int out_size, void* d_ws, size_t ws_size,
                              hipStream_t stream) {
    (void)in_sizes; (void)n_in; (void)out_size; (void)ws_size;
    const float* h   = (const float*)d_in[0];
    const int*   adj = (const int*)d_in[1];
    const float* W   = (const float*)d_in[2];
    const float* a   = (const float*)d_in[3];
    float* out = (float*)d_out;

    char* ws = (char*)d_ws;
    unsigned short* WhT = (unsigned short*)(ws);             // 12,582,912 B
    float*    s1    = (float*)(ws + 12582912);               // 64 KB each
    float*    s2    = (float*)(ws + 12648448);
    float*    E1    = (float*)(ws + 12713984);
    float*    E2    = (float*)(ws + 12779520);
    float*    Mb    = (float*)(ws + 12845056);               // 256 B
    unsigned* bits  = (unsigned*)(ws + 12845312);            // 512 KB
    int*      empty = (int*)(ws + 13369600);                 // 8 KB
    // total ~13.4 MB

    k_adjbits<<<512, 256, 0, stream>>>(adj, bits);
    k_wh<<<dim3(256, 8), 256, 0, stream>>>(h, W, a, WhT, s1, s2, E1, E2);
    k_aux<<<16, 256, 0, stream>>>(s1, bits, Mb, empty);
    k_gemm<<<512, 512, 0, stream>>>(WhT, s2, Mb, E1, E2, bits, empty, out);
}

// Round 7
// 265.120 us; speedup vs baseline: 1.0186x; 1.0186x over previous
//
#include <hip/hip_runtime.h>
#include <hip/hip_bf16.h>
#include <math.h>

// GAT layer: B=8, C_in=32, N=2048, L=12, F=32
// out[b,f,w,l] = elu( sum_v Wh[b,l,v,f] * attn[b,v,w] )
// attn = softmax_v( mask(adj, lrelu(s1[v]+s2[w])) )
// Factorized exp (per-batch global-max shift), denominator in-GEMM,
// K-split x2 with bf16 partials, 32x32x16 MFMA, tiled A layout.

constexpr int Nn  = 2048;
constexpr int Ln  = 12;
constexpr int Fn  = 32;
constexpr int LF  = 384;
constexpr int NW  = Nn / 32;     // 64
constexpr int CH  = 128;         // v per chunk
constexpr int KH  = 1024;        // K per block (split x2)
constexpr int NCH = KH / CH;     // 8
constexpr int WT  = 32;          // w per block

typedef short short8 __attribute__((ext_vector_type(8)));
typedef float f32x4  __attribute__((ext_vector_type(4)));
typedef float f32x16 __attribute__((ext_vector_type(16)));

static __device__ __forceinline__ unsigned short f2bf(float x) {
    unsigned u = __builtin_bit_cast(unsigned, x);
    u += 0x7FFFu + ((u >> 16) & 1u);
    return (unsigned short)(u >> 16);
}
static __device__ __forceinline__ float bf2f(unsigned u) {
    unsigned x = u << 16;
    return __builtin_bit_cast(float, x);
}

// ---------------------------------------------------------------------------
// 1. adj -> transposed bitmask
// ---------------------------------------------------------------------------
__global__ __launch_bounds__(256) void k_adjbits(const int* __restrict__ adj,
                                                 unsigned* __restrict__ bits) {
    int id = blockIdx.x * 256 + threadIdx.x;
    int w  = id & (Nn - 1);
    int vw = id >> 11;
    unsigned m = 0u;
    int base = vw * 32 * Nn + w;
    #pragma unroll
    for (int k = 0; k < 32; ++k)
        m |= (adj[base + k * Nn] > 0 ? 1u : 0u) << k;
    bits[w * NW + vw] = m;
}

// ---------------------------------------------------------------------------
// 2. Wh projection -> tiled WhT2[b][vo][lf][8v] (bf16), s1,s2,E1,E2
// ---------------------------------------------------------------------------
__global__ __launch_bounds__(256) void k_wh(const float* __restrict__ h,
                                            const float* __restrict__ W,
                                            const float* __restrict__ a,
                                            unsigned short* __restrict__ WhT2,
                                            float* __restrict__ s1,
                                            float* __restrict__ s2,
                                            float* __restrict__ E1,
                                            float* __restrict__ E2) {
    __shared__ float hs[96][33];
    __shared__ unsigned short T2[8][392];
    int b  = blockIdx.y;
    int n0 = blockIdx.x * 8;
    int tid = threadIdx.x;

    for (int i = tid; i < 32 * 96; i += 256) {
        int c = i / 96, r = i % 96;
        hs[r][c] = h[(size_t)(b * 32 + c) * (Nn * Ln) + n0 * Ln + r];
    }
    int f  = tid & 31;
    int nl = tid >> 5;
    float Wc[32];
    #pragma unroll
    for (int c = 0; c < 32; ++c) Wc[c] = W[c * 32 + f];
    __syncthreads();

    float last = 0.f;
    #pragma unroll
    for (int l = 0; l < Ln; ++l) {
        const float* hr = &hs[nl * Ln + l][0];
        float acc = 0.f;
        #pragma unroll
        for (int cq = 0; cq < 8; ++cq) {
            f32x4 hv = *(const f32x4*)(hr + cq * 4);
            acc = fmaf(hv[0], Wc[cq * 4 + 0], acc);
            acc = fmaf(hv[1], Wc[cq * 4 + 1], acc);
            acc = fmaf(hv[2], Wc[cq * 4 + 2], acc);
            acc = fmaf(hv[3], Wc[cq * 4 + 3], acc);
        }
        T2[nl][l * 32 + f] = f2bf(acc);
        if (l == Ln - 1) last = acc;
    }
    float r1 = last * a[f];
    float r2 = last * a[Fn + f];
    #pragma unroll
    for (int off = 16; off >= 1; off >>= 1) {
        r1 += __shfl_xor(r1, off);
        r2 += __shfl_xor(r2, off);
    }
    if (f == 0) {
        int n = n0 + nl;
        s1[b * Nn + n] = r1;
        s2[b * Nn + n] = r2;
        E1[b * Nn + n] = __expf(r1);
        E2[b * Nn + n] = __expf(0.2f * r1);
    }
    __syncthreads();
    // tiled store: uint4 index = (b*256 + vo)*384 + r  (fully contiguous)
    int vo = n0 >> 3;
    uint4* dst = (uint4*)WhT2 + ((size_t)b * 256 + vo) * LF;
    for (int r = tid; r < LF; r += 256) {
        unsigned d0 = (unsigned)T2[0][r] | ((unsigned)T2[1][r] << 16);
        unsigned d1 = (unsigned)T2[2][r] | ((unsigned)T2[3][r] << 16);
        unsigned d2 = (unsigned)T2[4][r] | ((unsigned)T2[5][r] << 16);
        unsigned d3 = (unsigned)T2[6][r] | ((unsigned)T2[7][r] << 16);
        dst[r] = (uint4){d0, d1, d2, d3};
    }
}

// ---------------------------------------------------------------------------
// 3. Aux: per-batch max of s1 (blocks 0-7), per-column empty flag (8-15)
// ---------------------------------------------------------------------------
__global__ __launch_bounds__(256) void k_aux(const float* __restrict__ s1,
                                             const unsigned* __restrict__ bits,
                                             float* __restrict__ Mb,
                                             int* __restrict__ empty) {
    if (blockIdx.x < 8) {
        int b = blockIdx.x;
        float m = -1e30f;
        for (int i = threadIdx.x; i < Nn; i += 256) m = fmaxf(m, s1[b * Nn + i]);
        #pragma unroll
        for (int off = 32; off >= 1; off >>= 1) m = fmaxf(m, __shfl_xor(m, off));
        __shared__ float wr[4];
        if ((threadIdx.x & 63) == 0) wr[threadIdx.x >> 6] = m;
        __syncthreads();
        if (threadIdx.x == 0)
            Mb[b] = fmaxf(fmaxf(wr[0], wr[1]), fmaxf(wr[2], wr[3]));
    } else {
        int w = (blockIdx.x - 8) * 256 + threadIdx.x;
        const uint4* p = (const uint4*)(bits + (size_t)w * NW);
        unsigned acc = 0;
        #pragma unroll
        for (int i = 0; i < 16; ++i) { uint4 v = p[i]; acc |= v.x | v.y | v.z | v.w; }
        empty[w] = (acc == 0u) ? 1 : 0;
    }
}

// ---------------------------------------------------------------------------
// 4. GEMM partial: block = 256 thr (4 waves), full M=384 (3x 32-row frags per
//    wave, 32x32x16 MFMA), WT=32 cols, K=1024 half. Grid 1024 = 4 blocks/CU.
//    P gen (16 elems/thread) into swizzled dbuf LDS; E/bits reg-prefetch.
//    Outputs bf16 partials hp[kh][b][lf][w] + f32 denom dpart[kh][b][w].
// ---------------------------------------------------------------------------
__global__ __launch_bounds__(256, 4) void k_gemm(const unsigned short* __restrict__ WhT2,
                                                 const float* __restrict__ s2,
                                                 const float* __restrict__ Mb,
                                                 const float* __restrict__ E1,
                                                 const float* __restrict__ E2,
                                                 const unsigned* __restrict__ bits,
                                                 const int* __restrict__ empty,
                                                 unsigned short* __restrict__ hp,
                                                 float* __restrict__ dpart) {
    int id = blockIdx.x;             // 1024; id&7==b -> one batch per XCD
    int b_ = id & 7;
    int kh = (id >> 3) & 1;
    int wt = id >> 4;                // 0..63
    int w0 = wt * WT;
    int tid  = threadIdx.x;
    int lane = tid & 63;
    int wv   = tid >> 6;             // wave 0..3
    int cl   = lane & 31;            // row (A) / col (B,D)
    int kg   = lane >> 5;            // k-octet group

    __shared__ unsigned short P[2][WT * CH];   // 16 KB, XOR-swizzled

    // gen mapping: wl = tid>>3 (0..31 w), vsub = (tid&7)*16 (16 v each)
    int wl   = tid >> 3;
    int vsub = (tid & 7) * 16;
    int w    = w0 + wl;

    float s2w = s2[(size_t)b_ * Nn + w];
    float mz  = Mb[b_] + s2w;
    float mw  = fmaxf(mz, 0.2f * mz);
    float F1  = __expf(s2w - mw);
    float F2  = __expf(0.2f * s2w - mw);
    float G   = __expf(-s2w);
    float Uv  = empty[w] ? 1.0f : 0.0f;
    float dsum = 0.f;

    const float* E1b = E1 + (size_t)b_ * Nn;
    const float* E2b = E2 + (size_t)b_ * Nn;
    const unsigned* bw = bits + (size_t)w * NW;

    auto ldE = [&](int c, f32x4 e1[4], f32x4 e2[4], unsigned& bm) {
        int v0 = kh * KH + c * CH + vsub;
        #pragma unroll
        for (int q = 0; q < 4; ++q) {
            e1[q] = *(const f32x4*)(E1b + v0 + q * 4);
            e2[q] = *(const f32x4*)(E2b + v0 + q * 4);
        }
        bm = (bw[v0 >> 5] >> (v0 & 31)) & 0xFFFFu;
    };

    auto gen = [&](int buf, const f32x4 e1[4], const f32x4 e2[4], unsigned bm) {
        #pragma unroll
        for (int o = 0; o < 2; ++o) {
            short8 sv;
            #pragma unroll
            for (int j = 0; j < 8; ++j) {
                int g = o * 8 + j;
                float e1v = e1[g >> 2][g & 3];
                float e2v = e2[g >> 2][g & 3];
                bool pos = e1v > G;
                float t = (pos ? e1v : e2v) * (pos ? F1 : F2);
                float p = ((bm >> g) & 1u) ? t : Uv;
                dsum += p;
                sv[j] = (short)f2bf(p);
            }
            int idx = (wl * CH + vsub + o * 8) ^ ((wl & 7) << 3);
            *(short8*)&P[buf][idx] = sv;
        }
    };

    f32x16 acc[3];
    #pragma unroll
    for (int f = 0; f < 3; ++f) acc[f] = (f32x16)(0.0f);

    const unsigned short* Ab = WhT2 + (size_t)b_ * 256 * LF * 8;

    auto mfma_chunk = [&](int c, int buf) {
        #pragma unroll
        for (int ks = 0; ks < 8; ++ks) {
            int vo = kh * 128 + c * 16 + ks * 2 + kg;
            int bidx = (cl * CH + ks * 16 + kg * 8) ^ ((cl & 7) << 3);
            short8 bfv = *(const short8*)&P[buf][bidx];
            #pragma unroll
            for (int f = 0; f < 3; ++f) {
                int rowA = (wv * 3 + f) * 32 + cl;
                short8 af = *(const short8*)(Ab + ((size_t)vo * LF + rowA) * 8);
                acc[f] = __builtin_amdgcn_mfma_f32_32x32x16_bf16(af, bfv, acc[f], 0, 0, 0);
            }
        }
    };

    {
        f32x4 e1c[4], e2c[4]; unsigned bmc;
        ldE(0, e1c, e2c, bmc);
        gen(0, e1c, e2c, bmc);
    }
    __syncthreads();

    for (int c = 0; c < NCH; ++c) {
        f32x4 e1n[4], e2n[4]; unsigned bmn = 0;
        if (c + 1 < NCH) ldE(c + 1, e1n, e2n, bmn);   // issue before MFMA phase
        __builtin_amdgcn_s_setprio(1);
        mfma_chunk(c, c & 1);
        __builtin_amdgcn_s_setprio(0);
        if (c + 1 < NCH) gen((c + 1) & 1, e1n, e2n, bmn);
        __syncthreads();
    }

    // bf16 partial stores: D layout col=lane&31, row=(q&3)+8*(q>>2)+4*(lane>>5)
    unsigned short* hpb = hp + ((size_t)(kh * 8 + b_) * LF) * Nn;
    #pragma unroll
    for (int f = 0; f < 3; ++f)
        #pragma unroll
        for (int q = 0; q < 16; ++q) {
            int rowG = (wv * 3 + f) * 32 + (q & 3) + 8 * (q >> 2) + 4 * kg;
            hpb[(size_t)rowG * Nn + w0 + cl] = f2bf(acc[f][q]);
        }

    // denom partial: reduce the 8 v-threads (consecutive lanes) per w
    #pragma unroll
    for (int off = 1; off < 8; off <<= 1) dsum += __shfl_xor(dsum, off);
    if ((tid & 7) == 0) dpart[(size_t)(kh * 8 + b_) * Nn + w] = dsum;
}

// ---------------------------------------------------------------------------
// 5. Finalize: out[b,f,w,l] = elu( (hp0+hp1)/(d0+d1) ), coalesced both sides
// ---------------------------------------------------------------------------
__global__ __launch_bounds__(256) void k_fin(const unsigned short* __restrict__ hp,
                                             const float* __restrict__ dpart,
                                             float* __restrict__ out) {
    int idb = blockIdx.x;            // 256 = 8 b * 32 f
    int b = idb >> 5, f = idb & 31;
    const unsigned short* hp0 = hp + ((size_t)b * LF) * Nn;
    const unsigned short* hp1 = hp + ((size_t)(8 + b) * LF) * Nn;
    for (int pass = 0; pass < 4; ++pass) {
        int w2 = pass * 512 + threadIdx.x * 2;
        float dA = dpart[(size_t)b * Nn + w2]     + dpart[(size_t)(8 + b) * Nn + w2];
        float dB = dpart[(size_t)b * Nn + w2 + 1] + dpart[(size_t)(8 + b) * Nn + w2 + 1];
        float rdA = 1.f / dA, rdB = 1.f / dB;
        float vA[12], vB[12];
        #pragma unroll
        for (int l = 0; l < Ln; ++l) {
            int row = l * 32 + f;
            unsigned u0 = *(const unsigned*)&hp0[(size_t)row * Nn + w2];
            unsigned u1 = *(const unsigned*)&hp1[(size_t)row * Nn + w2];
            float lo = (bf2f(u0 & 0xFFFFu) + bf2f(u1 & 0xFFFFu)) * rdA;
            float hi = (bf2f(u0 >> 16)     + bf2f(u1 >> 16))     * rdB;
            vA[l] = (lo > 0.f) ? lo : expm1f(lo);
            vB[l] = (hi > 0.f) ? hi : expm1f(hi);
        }
        float* ob = out + ((size_t)(b * Fn + f) * Nn + w2) * Ln;
        *(f32x4*)(ob + 0)  = (f32x4){vA[0], vA[1], vA[2],  vA[3]};
        *(f32x4*)(ob + 4)  = (f32x4){vA[4], vA[5], vA[6],  vA[7]};
        *(f32x4*)(ob + 8)  = (f32x4){vA[8], vA[9], vA[10], vA[11]};
        *(f32x4*)(ob + 12) = (f32x4){vB[0], vB[1], vB[2],  vB[3]};
        *(f32x4*)(ob + 16) = (f32x4){vB[4], vB[5], vB[6],  vB[7]};
        *(f32x4*)(ob + 20) = (f32x4){vB[8], vB[9], vB[10], vB[11]};
    }
}

// ---------------------------------------------------------------------------
extern "C" void kernel_launch(void* const* d_in, const int* in_sizes, int n_in,
                              void* d_out, int out_size, void* d_ws, size_t ws_size,
                              hipStream_t stream) {
    (void)in_sizes; (void)n_in; (void)out_size; (void)ws_size;
    const float* h   = (const float*)d_in[0];
    const int*   adj = (const int*)d_in[1];
    const float* W   = (const float*)d_in[2];
    const float* a   = (const float*)d_in[3];
    float* out = (float*)d_out;

    char* ws = (char*)d_ws;
    unsigned short* WhT2 = (unsigned short*)(ws);            // 12,582,912
    float*    s1    = (float*)(ws + 12582912);               // 64 KB each
    float*    s2    = (float*)(ws + 12648448);
    float*    E1    = (float*)(ws + 12713984);
    float*    E2    = (float*)(ws + 12779520);
    float*    Mb    = (float*)(ws + 12845056);               // 256 B
    unsigned* bits  = (unsigned*)(ws + 12845312);            // 512 KB
    int*      empty = (int*)(ws + 13369600);                 // 8 KB
    float*    dpart = (float*)(ws + 13377792);               // 128 KB
    unsigned short* hp = (unsigned short*)(ws + 13508864);   // 25,165,824
    // total ~38.7 MB

    k_adjbits<<<512, 256, 0, stream>>>(adj, bits);
    k_wh<<<dim3(256, 8), 256, 0, stream>>>(h, W, a, WhT2, s1, s2, E1, E2);
    k_aux<<<16, 256, 0, stream>>>(s1, bits, Mb, empty);
    k_gemm<<<1024, 256, 0, stream>>>(WhT2, s2, Mb, E1, E2, bits, empty, hp, dpart);
    k_fin<<<256, 256, 0, stream>>>(hp, dpart, out);
}

// Round 8
// 189.151 us; speedup vs baseline: 1.4277x; 1.4016x over previous
//
#include <hip/hip_runtime.h>
#include <hip/hip_bf16.h>
#include <math.h>

// GAT layer: B=8, C_in=32, N=2048, L=12, F=32
// out[b,f,w,l] = elu( sum_v Wh[b,l,v,f] * attn[b,v,w] )
// attn = softmax_v( mask(adj, lrelu(s1[v]+s2[w])) )
// Factorized exp (per-batch global-max shift), denominator in-GEMM,
// K-split x2 with bf16 partials, 32x32x16 MFMA, tiled A layout.

constexpr int Nn  = 2048;
constexpr int Ln  = 12;
constexpr int Fn  = 32;
constexpr int LF  = 384;
constexpr int NW  = Nn / 32;     // 64
constexpr int CH  = 128;         // v per chunk
constexpr int KH  = 1024;        // K per block (split x2)
constexpr int NCH = KH / CH;     // 8
constexpr int WT  = 32;          // w per block

typedef short short8 __attribute__((ext_vector_type(8)));
typedef float f32x4  __attribute__((ext_vector_type(4)));
typedef float f32x16 __attribute__((ext_vector_type(16)));

static __device__ __forceinline__ unsigned short f2bf(float x) {
    unsigned u = __builtin_bit_cast(unsigned, x);
    u += 0x7FFFu + ((u >> 16) & 1u);
    return (unsigned short)(u >> 16);
}
static __device__ __forceinline__ float bf2f(unsigned u) {
    unsigned x = u << 16;
    return __builtin_bit_cast(float, x);
}

// ---------------------------------------------------------------------------
// 1. adj -> transposed bitmask
// ---------------------------------------------------------------------------
__global__ __launch_bounds__(256) void k_adjbits(const int* __restrict__ adj,
                                                 unsigned* __restrict__ bits) {
    int id = blockIdx.x * 256 + threadIdx.x;
    int w  = id & (Nn - 1);
    int vw = id >> 11;
    unsigned m = 0u;
    int base = vw * 32 * Nn + w;
    #pragma unroll
    for (int k = 0; k < 32; ++k)
        m |= (adj[base + k * Nn] > 0 ? 1u : 0u) << k;
    bits[w * NW + vw] = m;
}

// ---------------------------------------------------------------------------
// 2. Wh projection, LDS-free compute. Block = 384 thr = 32 n x 12 l, one b.
//    Thread owns one (n,l) row: gathers its 32 h values (coalesced 4B/lane),
//    runs 1024 FMAs into 32 independent acc chains with W via scalar loads
//    (wave-uniform index -> SGPR), then one LDS transpose for tiled stores.
//    l==11 threads compute s1/s2 as per-thread dot products + E1/E2.
// ---------------------------------------------------------------------------
__global__ __launch_bounds__(384) void k_wh(const float* __restrict__ h,
                                            const float* __restrict__ W,
                                            const float* __restrict__ a,
                                            unsigned short* __restrict__ WhT2,
                                            float* __restrict__ s1,
                                            float* __restrict__ s2,
                                            float* __restrict__ E1,
                                            float* __restrict__ E2) {
    __shared__ unsigned short T[32][392];        // 24.5 KB
    int b  = blockIdx.y;
    int n0 = blockIdx.x * 32;
    int t  = threadIdx.x;        // 0..383
    int nl = t / 12;             // 0..31
    int l  = t - nl * 12;

    // gather h[b][c][(n0*12 + t)] for c = 0..31 (consecutive t -> consecutive addr)
    const float* hb = h + ((size_t)b * 32 * Nn + n0) * Ln;
    float hv[32];
    #pragma unroll
    for (int c = 0; c < 32; ++c) hv[c] = hb[(size_t)c * Nn * Ln + t];

    float acc[32];
    #pragma unroll
    for (int f = 0; f < 32; ++f) acc[f] = 0.f;
    #pragma unroll 8
    for (int c = 0; c < 32; ++c) {
        float hc = hv[c];
        #pragma unroll
        for (int f = 0; f < 32; ++f)
            acc[f] = fmaf(hc, W[c * 32 + f], acc[f]);   // W: uniform -> s_load
    }

    // stage bf16 row into LDS: T[nl][l*32 + f]
    #pragma unroll
    for (int q = 0; q < 4; ++q) {
        unsigned d0 = (unsigned)f2bf(acc[q * 8 + 0]) | ((unsigned)f2bf(acc[q * 8 + 1]) << 16);
        unsigned d1 = (unsigned)f2bf(acc[q * 8 + 2]) | ((unsigned)f2bf(acc[q * 8 + 3]) << 16);
        unsigned d2 = (unsigned)f2bf(acc[q * 8 + 4]) | ((unsigned)f2bf(acc[q * 8 + 5]) << 16);
        unsigned d3 = (unsigned)f2bf(acc[q * 8 + 6]) | ((unsigned)f2bf(acc[q * 8 + 7]) << 16);
        *(uint4*)&T[nl][l * 32 + q * 8] = (uint4){d0, d1, d2, d3};
    }

    if (l == Ln - 1) {
        float r1 = 0.f, r2 = 0.f;
        #pragma unroll
        for (int f = 0; f < 32; ++f) {
            r1 = fmaf(acc[f], a[f], r1);
            r2 = fmaf(acc[f], a[Fn + f], r2);
        }
        int n = n0 + nl;
        s1[b * Nn + n] = r1;
        s2[b * Nn + n] = r2;
        E1[b * Nn + n] = __expf(r1);
        E2[b * Nn + n] = __expf(0.2f * r1);
    }
    __syncthreads();

    // store phase: thread t owns lf row r=t; 4 vo-groups, fully coalesced 16B
    {
        int r = t;
        uint4* dst = (uint4*)WhT2 + ((size_t)b * 256 + (n0 >> 3)) * LF;
        #pragma unroll
        for (int vv = 0; vv < 4; ++vv) {
            unsigned d0 = (unsigned)T[vv * 8 + 0][r] | ((unsigned)T[vv * 8 + 1][r] << 16);
            unsigned d1 = (unsigned)T[vv * 8 + 2][r] | ((unsigned)T[vv * 8 + 3][r] << 16);
            unsigned d2 = (unsigned)T[vv * 8 + 4][r] | ((unsigned)T[vv * 8 + 5][r] << 16);
            unsigned d3 = (unsigned)T[vv * 8 + 6][r] | ((unsigned)T[vv * 8 + 7][r] << 16);
            dst[(size_t)vv * LF + r] = (uint4){d0, d1, d2, d3};
        }
    }
}

// ---------------------------------------------------------------------------
// 3. Aux: per-batch max of s1 (blocks 0-7), per-column empty flag (8-15)
// ---------------------------------------------------------------------------
__global__ __launch_bounds__(256) void k_aux(const float* __restrict__ s1,
                                             const unsigned* __restrict__ bits,
                                             float* __restrict__ Mb,
                                             int* __restrict__ empty) {
    if (blockIdx.x < 8) {
        int b = blockIdx.x;
        float m = -1e30f;
        for (int i = threadIdx.x; i < Nn; i += 256) m = fmaxf(m, s1[b * Nn + i]);
        #pragma unroll
        for (int off = 32; off >= 1; off >>= 1) m = fmaxf(m, __shfl_xor(m, off));
        __shared__ float wr[4];
        if ((threadIdx.x & 63) == 0) wr[threadIdx.x >> 6] = m;
        __syncthreads();
        if (threadIdx.x == 0)
            Mb[b] = fmaxf(fmaxf(wr[0], wr[1]), fmaxf(wr[2], wr[3]));
    } else {
        int w = (blockIdx.x - 8) * 256 + threadIdx.x;
        const uint4* p = (const uint4*)(bits + (size_t)w * NW);
        unsigned acc = 0;
        #pragma unroll
        for (int i = 0; i < 16; ++i) { uint4 v = p[i]; acc |= v.x | v.y | v.z | v.w; }
        empty[w] = (acc == 0u) ? 1 : 0;
    }
}

// ---------------------------------------------------------------------------
// 4. GEMM partial: block = 256 thr (4 waves), full M=384 (3x 32-row frags per
//    wave, 32x32x16 MFMA), WT=32 cols, K=1024 half. Grid 1024 = 4 blocks/CU.
//    P gen (16 elems/thread) into swizzled dbuf LDS; E/bits reg-prefetch.
//    Outputs bf16 partials hp[kh][b][lf][w] + f32 denom dpart[kh][b][w].
// ---------------------------------------------------------------------------
__global__ __launch_bounds__(256, 4) void k_gemm(const unsigned short* __restrict__ WhT2,
                                                 const float* __restrict__ s2,
                                                 const float* __restrict__ Mb,
                                                 const float* __restrict__ E1,
                                                 const float* __restrict__ E2,
                                                 const unsigned* __restrict__ bits,
                                                 const int* __restrict__ empty,
                                                 unsigned short* __restrict__ hp,
                                                 float* __restrict__ dpart) {
    int id = blockIdx.x;             // 1024; id&7==b -> one batch per XCD
    int b_ = id & 7;
    int kh = (id >> 3) & 1;
    int wt = id >> 4;                // 0..63
    int w0 = wt * WT;
    int tid  = threadIdx.x;
    int lane = tid & 63;
    int wv   = tid >> 6;             // wave 0..3
    int cl   = lane & 31;            // row (A) / col (B,D)
    int kg   = lane >> 5;            // k-octet group

    __shared__ unsigned short P[2][WT * CH];   // 16 KB, XOR-swizzled

    // gen mapping: wl = tid>>3 (0..31 w), vsub = (tid&7)*16 (16 v each)
    int wl   = tid >> 3;
    int vsub = (tid & 7) * 16;
    int w    = w0 + wl;

    float s2w = s2[(size_t)b_ * Nn + w];
    float mz  = Mb[b_] + s2w;
    float mw  = fmaxf(mz, 0.2f * mz);
    float F1  = __expf(s2w - mw);
    float F2  = __expf(0.2f * s2w - mw);
    float G   = __expf(-s2w);
    float Uv  = empty[w] ? 1.0f : 0.0f;
    float dsum = 0.f;

    const float* E1b = E1 + (size_t)b_ * Nn;
    const float* E2b = E2 + (size_t)b_ * Nn;
    const unsigned* bw = bits + (size_t)w * NW;

    auto ldE = [&](int c, f32x4 e1[4], f32x4 e2[4], unsigned& bm) {
        int v0 = kh * KH + c * CH + vsub;
        #pragma unroll
        for (int q = 0; q < 4; ++q) {
            e1[q] = *(const f32x4*)(E1b + v0 + q * 4);
            e2[q] = *(const f32x4*)(E2b + v0 + q * 4);
        }
        bm = (bw[v0 >> 5] >> (v0 & 31)) & 0xFFFFu;
    };

    auto gen = [&](int buf, const f32x4 e1[4], const f32x4 e2[4], unsigned bm) {
        #pragma unroll
        for (int o = 0; o < 2; ++o) {
            short8 sv;
            #pragma unroll
            for (int j = 0; j < 8; ++j) {
                int g = o * 8 + j;
                float e1v = e1[g >> 2][g & 3];
                float e2v = e2[g >> 2][g & 3];
                bool pos = e1v > G;
                float t = (pos ? e1v : e2v) * (pos ? F1 : F2);
                float p = ((bm >> g) & 1u) ? t : Uv;
                dsum += p;
                sv[j] = (short)f2bf(p);
            }
            int idx = (wl * CH + vsub + o * 8) ^ ((wl & 7) << 3);
            *(short8*)&P[buf][idx] = sv;
        }
    };

    f32x16 acc[3];
    #pragma unroll
    for (int f = 0; f < 3; ++f) acc[f] = (f32x16)(0.0f);

    const unsigned short* Ab = WhT2 + (size_t)b_ * 256 * LF * 8;

    auto mfma_chunk = [&](int c, int buf) {
        #pragma unroll
        for (int ks = 0; ks < 8; ++ks) {
            int vo = kh * 128 + c * 16 + ks * 2 + kg;
            int bidx = (cl * CH + ks * 16 + kg * 8) ^ ((cl & 7) << 3);
            short8 bfv = *(const short8*)&P[buf][bidx];
            #pragma unroll
            for (int f = 0; f < 3; ++f) {
                int rowA = (wv * 3 + f) * 32 + cl;
                short8 af = *(const short8*)(Ab + ((size_t)vo * LF + rowA) * 8);
                acc[f] = __builtin_amdgcn_mfma_f32_32x32x16_bf16(af, bfv, acc[f], 0, 0, 0);
            }
        }
    };

    {
        f32x4 e1c[4], e2c[4]; unsigned bmc;
        ldE(0, e1c, e2c, bmc);
        gen(0, e1c, e2c, bmc);
    }
    __syncthreads();

    for (int c = 0; c < NCH; ++c) {
        f32x4 e1n[4], e2n[4]; unsigned bmn = 0;
        if (c + 1 < NCH) ldE(c + 1, e1n, e2n, bmn);   // issue before MFMA phase
        __builtin_amdgcn_s_setprio(1);
        mfma_chunk(c, c & 1);
        __builtin_amdgcn_s_setprio(0);
        if (c + 1 < NCH) gen((c + 1) & 1, e1n, e2n, bmn);
        __syncthreads();
    }

    // bf16 partial stores: D layout col=lane&31, row=(q&3)+8*(q>>2)+4*(lane>>5)
    unsigned short* hpb = hp + ((size_t)(kh * 8 + b_) * LF) * Nn;
    #pragma unroll
    for (int f = 0; f < 3; ++f)
        #pragma unroll
        for (int q = 0; q < 16; ++q) {
            int rowG = (wv * 3 + f) * 32 + (q & 3) + 8 * (q >> 2) + 4 * kg;
            hpb[(size_t)rowG * Nn + w0 + cl] = f2bf(acc[f][q]);
        }

    // denom partial: reduce the 8 v-threads (consecutive lanes) per w
    #pragma unroll
    for (int off = 1; off < 8; off <<= 1) dsum += __shfl_xor(dsum, off);
    if ((tid & 7) == 0) dpart[(size_t)(kh * 8 + b_) * Nn + w] = dsum;
}

// ---------------------------------------------------------------------------
// 5. Finalize: out[b,f,w,l] = elu( (hp0+hp1)/(d0+d1) ); grid (256, 4 passes)
// ---------------------------------------------------------------------------
__global__ __launch_bounds__(256) void k_fin(const unsigned short* __restrict__ hp,
                                             const float* __restrict__ dpart,
                                             float* __restrict__ out) {
    int idb = blockIdx.x;            // 256 = 8 b * 32 f
    int b = idb >> 5, f = idb & 31;
    const unsigned short* hp0 = hp + ((size_t)b * LF) * Nn;
    const unsigned short* hp1 = hp + ((size_t)(8 + b) * LF) * Nn;
    int w2 = blockIdx.y * 512 + threadIdx.x * 2;
    float dA = dpart[(size_t)b * Nn + w2]     + dpart[(size_t)(8 + b) * Nn + w2];
    float dB = dpart[(size_t)b * Nn + w2 + 1] + dpart[(size_t)(8 + b) * Nn + w2 + 1];
    float rdA = 1.f / dA, rdB = 1.f / dB;
    float vA[12], vB[12];
    #pragma unroll
    for (int l = 0; l < Ln; ++l) {
        int row = l * 32 + f;
        unsigned u0 = *(const unsigned*)&hp0[(size_t)row * Nn + w2];
        unsigned u1 = *(const unsigned*)&hp1[(size_t)row * Nn + w2];
        float lo = (bf2f(u0 & 0xFFFFu) + bf2f(u1 & 0xFFFFu)) * rdA;
        float hi = (bf2f(u0 >> 16)     + bf2f(u1 >> 16))     * rdB;
        vA[l] = (lo > 0.f) ? lo : (__expf(lo) - 1.0f);
        vB[l] = (hi > 0.f) ? hi : (__expf(hi) - 1.0f);
    }
    float* ob = out + ((size_t)(b * Fn + f) * Nn + w2) * Ln;
    *(f32x4*)(ob + 0)  = (f32x4){vA[0], vA[1], vA[2],  vA[3]};
    *(f32x4*)(ob + 4)  = (f32x4){vA[4], vA[5], vA[6],  vA[7]};
    *(f32x4*)(ob + 8)  = (f32x4){vA[8], vA[9], vA[10], vA[11]};
    *(f32x4*)(ob + 12) = (f32x4){vB[0], vB[1], vB[2],  vB[3]};
    *(f32x4*)(ob + 16) = (f32x4){vB[4], vB[5], vB[6],  vB[7]};
    *(f32x4*)(ob + 20) = (f32x4){vB[8], vB[9], vB[10], vB[11]};
}

// ---------------------------------------------------------------------------
extern "C" void kernel_launch(void* const* d_in, const int* in_sizes, int n_in,
                              void* d_out, int out_size, void* d_ws, size_t ws_size,
                              hipStream_t stream) {
    (void)in_sizes; (void)n_in; (void)out_size; (void)ws_size;
    const float* h   = (const float*)d_in[0];
    const int*   adj = (const int*)d_in[1];
    const float* W   = (const float*)d_in[2];
    const float* a   = (const float*)d_in[3];
    float* out = (float*)d_out;

    char* ws = (char*)d_ws;
    unsigned short* WhT2 = (unsigned short*)(ws);            // 12,582,912
    float*    s1    = (float*)(ws + 12582912);               // 64 KB each
    float*    s2    = (float*)(ws + 12648448);
    float*    E1    = (float*)(ws + 12713984);
    float*    E2    = (float*)(ws + 12779520);
    float*    Mb    = (float*)(ws + 12845056);               // 256 B
    unsigned* bits  = (unsigned*)(ws + 12845312);            // 512 KB
    int*      empty = (int*)(ws + 13369600);                 // 8 KB
    float*    dpart = (float*)(ws + 13377792);               // 128 KB
    unsigned short* hp = (unsigned short*)(ws + 13508864);   // 25,165,824
    // total ~38.7 MB

    k_adjbits<<<512, 256, 0, stream>>>(adj, bits);
    k_wh<<<dim3(64, 8), 384, 0, stream>>>(h, W, a, WhT2, s1, s2, E1, E2);
    k_aux<<<16, 256, 0, stream>>>(s1, bits, Mb, empty);
    k_gemm<<<1024, 256, 0, stream>>>(WhT2, s2, Mb, E1, E2, bits, empty, hp, dpart);
    k_fin<<<dim3(256, 4), 256, 0, stream>>>(hp, dpart, out);
}